// Round 17
// baseline (541.482 us; speedup 1.0000x reference)
//
#include <hip/hip_runtime.h>
#include <hip/hip_bf16.h>

#define Dd 1024
#define Hh 4096
#define Ee 8
#define Tt 4096   // tokens = 2*2048
#define Kk 2

typedef __attribute__((ext_vector_type(8))) short short8;
typedef __attribute__((ext_vector_type(4))) float f32x4;

__device__ __forceinline__ unsigned short f2bf_bits(float f) {
  unsigned u = __builtin_bit_cast(unsigned, f);
  u += 0x7FFFu + ((u >> 16) & 1u);   // RNE (finite values)
  return (unsigned short)(u >> 16);
}

__device__ __forceinline__ void glds16(const void* g, void* l) {
  __builtin_amdgcn_global_load_lds(
      (const __attribute__((address_space(1))) unsigned int*)g,
      (__attribute__((address_space(3))) unsigned int*)l, 16, 0, 0);
}

// ---------------- fp32 -> bf16 conversion (vectorized) ----------------
__global__ __launch_bounds__(256) void cvt_kernel(const float* __restrict__ src,
                                                  unsigned short* __restrict__ dst, int n4) {
  int i = blockIdx.x * blockDim.x + threadIdx.x;
  int stride = gridDim.x * blockDim.x;
  for (; i < n4; i += stride) {
    float4 v = reinterpret_cast<const float4*>(src)[i];
    ushort4 o;
    o.x = f2bf_bits(v.x);
    o.y = f2bf_bits(v.y);
    o.z = f2bf_bits(v.z);
    o.w = f2bf_bits(v.w);
    reinterpret_cast<ushort4*>(dst)[i] = o;
  }
}

// ---------------- router: softmax + top-2 + expert lists + fused token gather ----------------
__global__ __launch_bounds__(256) void router_kernel(
    const float* __restrict__ x, const float* __restrict__ Wr, const float* __restrict__ br,
    int* __restrict__ cnt, int* __restrict__ list, float* __restrict__ g2,
    unsigned short* __restrict__ xg) {
  int t = blockIdx.x * 4 + (threadIdx.x >> 6);
  int lane = threadIdx.x & 63;
  const float* xr = x + (size_t)t * Dd;
  float pe[Ee];
#pragma unroll
  for (int e = 0; e < Ee; e++) pe[e] = 0.f;
  for (int d = lane; d < Dd; d += 64) {
    float xv = xr[d];
#pragma unroll
    for (int e = 0; e < Ee; e++) pe[e] += xv * Wr[e * Dd + d];
  }
#pragma unroll
  for (int e = 0; e < Ee; e++) {
    float v = pe[e];
#pragma unroll
    for (int s = 32; s > 0; s >>= 1) v += __shfl_xor(v, s);
    pe[e] = v + br[e];
  }
  int e0 = 0, e1 = 0, p0 = 0, p1 = 0;
  if (lane == 0) {
    float mx = pe[0];
#pragma unroll
    for (int e = 1; e < Ee; e++) mx = fmaxf(mx, pe[e]);
    float g[Ee];
    float sum = 0.f;
#pragma unroll
    for (int e = 0; e < Ee; e++) { g[e] = expf(pe[e] - mx); sum += g[e]; }
    float inv = 1.0f / sum;
    float g0v = g[0];
#pragma unroll
    for (int e = 1; e < Ee; e++) if (g[e] > g0v) { g0v = g[e]; e0 = e; }
    float g1v = -1.f;
#pragma unroll
    for (int e = 0; e < Ee; e++) if (e != e0 && g[e] > g1v) { g1v = g[e]; e1 = e; }
    g2[t * 2 + 0] = g0v * inv;
    g2[t * 2 + 1] = g1v * inv;
    p0 = atomicAdd(&cnt[e0], 1);
    list[e0 * Tt + p0] = t * 2;
    p1 = atomicAdd(&cnt[e1], 1);
    list[e1 * Tt + p1] = t * 2 + 1;
  }
  e0 = __shfl(e0, 0); p0 = __shfl(p0, 0);
  e1 = __shfl(e1, 0); p1 = __shfl(p1, 0);
  ushort4* r0 = (ushort4*)(xg + ((size_t)e0 * Tt + p0) * Dd);
  ushort4* r1 = (ushort4*)(xg + ((size_t)e1 * Tt + p1) * Dd);
  const float4* x4 = reinterpret_cast<const float4*>(xr);
  for (int c = lane; c < Dd / 4; c += 64) {
    float4 v = x4[c];
    ushort4 o;
    o.x = f2bf_bits(v.x);
    o.y = f2bf_bits(v.y);
    o.z = f2bf_bits(v.z);
    o.w = f2bf_bits(v.w);
    r0[c] = o;
    r1[c] = o;
  }
}

// meta: [0..7]=row offs, [8..15]=m_e=ceil(ce/128)
__global__ void scan_kernel(const int* __restrict__ cnt, int* __restrict__ meta) {
  if (threadIdx.x == 0 && blockIdx.x == 0) {
    int a = 0;
    for (int e = 0; e < Ee; e++) {
      meta[e] = a; a += cnt[e];
      meta[8 + e] = (cnt[e] + 127) >> 7;
    }
  }
}

// ========== 128x128 tile, BK=32, 4 waves (2x2) — m97-discipline (single buffer, drain) ====
// LDS per operand: ONE buffer [row(128)][32 shorts] = 8 KB (A+B = 16 KB total).
// Per K-step: STAGE (4 glds/thread) -> vmcnt(0) -> barrier -> COMPUTE -> barrier.
// ZERO standing VMEM queue (r9-r16's counted-vmcnt kept 64-512KB in flight per CU ->
// queue-latency ~13Kcy/step; m97's drain runs 736 cy/step).
// Layout/swizzle r12-proven (0 conflicts): staging 4 lanes/row (fully-used 64B lines),
// source granule pre-swizzle (tid&3)^((row>>1)&3), read granule kq^((fr>>1)&3).

#define STAGE(k0)                                      \
  do {                                                 \
    glds16(aS0 + (k0), AsW);                           \
    glds16(aS1 + (k0), AsW + 2048);                    \
    glds16(bS0 + (k0), BsW);                           \
    glds16(bS1 + (k0), BsW + 2048);                    \
  } while (0)

#define COMPUTE()                                                               \
  do {                                                                          \
    short8 af[4], bv[4];                                                        \
    _Pragma("unroll") for (int i = 0; i < 4; i++)                               \
        af[i] = *reinterpret_cast<const short8*>(                               \
            &As[(wm * 64 + i * 16 + fr) * 32 + gph]);                           \
    _Pragma("unroll") for (int j = 0; j < 4; j++)                               \
        bv[j] = *reinterpret_cast<const short8*>(                               \
            &Bs[(wn * 64 + j * 16 + fr) * 32 + gph]);                           \
    _Pragma("unroll") for (int i = 0; i < 4; i++)                               \
      _Pragma("unroll") for (int j = 0; j < 4; j++)                             \
          acc[i][j] = __builtin_amdgcn_mfma_f32_16x16x32_bf16(af[i], bv[j],     \
                                                              acc[i][j], 0, 0, 0); \
  } while (0)

#define PIPELINE(NKT)                                              \
  do {                                                             \
    for (int kt = 0; kt < (NKT); ++kt) {                           \
      STAGE(kt * 32);                                              \
      asm volatile("s_waitcnt vmcnt(0)" ::: "memory");             \
      __builtin_amdgcn_s_barrier();                                \
      COMPUTE();                                                   \
      __builtin_amdgcn_s_barrier();                                \
    }                                                              \
  } while (0)

// ---------------- GEMM1: h = gelu(xg @ W1[e]^T + b1[e]) -> bf16 ----------------
__global__ __launch_bounds__(256) void gemm1_kernel(
    const unsigned short* __restrict__ xg, const unsigned short* __restrict__ w1b,
    const float* __restrict__ b1,
    const int* __restrict__ cnt, const int* __restrict__ meta,
    unsigned short* __restrict__ hb) {
  int e = blockIdx.x & 7;
  int G = gridDim.x >> 3;
  int m_e = meta[8 + e];
  int ce = cnt[e], off_e = meta[e];
  int span = m_e * (Hh / 128);

  __shared__ short As[4096];
  __shared__ short Bs[4096];

  int tid = threadIdx.x;
  int lane = tid & 63;
  int w = tid >> 6;
  int wm = w >> 1, wn = w & 1;
  int fr = lane & 15, kq = lane >> 4;

  int r0 = tid >> 2;                               // staging row 0..63 (second set +64)
  int swz = ((tid & 3) ^ ((r0 >> 1) & 3)) << 3;    // source granule pre-swizzle (elems)
  short* AsW = &As[w * 512];
  short* BsW = &Bs[w * 512];
  int gph = (kq ^ ((fr >> 1) & 3)) << 3;           // read-side physical granule
  const float* b1e = b1 + (size_t)e * Hh;

  for (int local = blockIdx.x >> 3; local < span; local += G) {
    int nt = local / m_e, mt = local % m_e;        // mt-inner: consecutive share B-panel
    __syncthreads();                               // prev tile's LDS readers done

    const unsigned short* aS0 = xg + (size_t)e * Tt * Dd + (size_t)(mt * 128 + r0) * Dd + swz;
    const unsigned short* aS1 = aS0 + (size_t)64 * Dd;
    const unsigned short* bS0 = w1b + (size_t)e * Hh * Dd + (size_t)(nt * 128 + r0) * Dd + swz;
    const unsigned short* bS1 = bS0 + (size_t)64 * Dd;

    float biasj[4];
#pragma unroll
    for (int j = 0; j < 4; j++) biasj[j] = b1e[nt * 128 + wn * 64 + j * 16 + fr];

    f32x4 acc[4][4] = {};
    PIPELINE(Dd / 32);   // 32 K-steps

#pragma unroll
    for (int i = 0; i < 4; i++) {
      int rb = wm * 64 + i * 16 + kq * 4;
#pragma unroll
      for (int j = 0; j < 4; j++) {
        int col = nt * 128 + wn * 64 + j * 16 + fr;
#pragma unroll
        for (int rr = 0; rr < 4; rr++) {
          int grow = mt * 128 + rb + rr;
          if (grow < ce) {
            float v = acc[i][j][rr] + biasj[j];
            v = 0.5f * v * (1.0f + erff(v * 0.70710678118654752f));
            hb[(size_t)(off_e + grow) * Hh + col] = f2bf_bits(v);
          }
        }
      }
    }
  }
}

// ------- GEMM2: split-K=2 no atomics: y[ks][en] = h@W2[e]^T (+b2 if ks==0) --------
__global__ __launch_bounds__(256) void gemm2_kernel(
    const unsigned short* __restrict__ hb, const unsigned short* __restrict__ w2b,
    const float* __restrict__ b2,
    const int* __restrict__ cnt, const int* __restrict__ meta, const int* __restrict__ list,
    float* __restrict__ yb) {
  int e = blockIdx.x & 7;
  int G = gridDim.x >> 3;
  int m_e = meta[8 + e];
  int ce = cnt[e], off_e = meta[e];
  int span = m_e * (Dd / 128) * 2;

  __shared__ short As[4096];
  __shared__ short Bs[4096];

  int tid = threadIdx.x;
  int lane = tid & 63;
  int w = tid >> 6;
  int wm = w >> 1, wn = w & 1;
  int fr = lane & 15, kq = lane >> 4;

  int r0 = tid >> 2;
  int swz = ((tid & 3) ^ ((r0 >> 1) & 3)) << 3;
  short* AsW = &As[w * 512];
  short* BsW = &Bs[w * 512];
  int gph = (kq ^ ((fr >> 1) & 3)) << 3;
  const int* le = list + e * Tt;
  const float* b2e = b2 + (size_t)e * Dd;

  for (int local = blockIdx.x >> 3; local < span; local += G) {
    int g = local / m_e, mt = local % m_e;   // mt-inner within each (nt,ks) group
    int nt = g >> 1, ks = g & 1;
    __syncthreads();

    // hb is padded +256 rows -> no clamps needed (overrun rows garbage, outputs guarded)
    const unsigned short* aS0 = hb + (size_t)(off_e + mt * 128 + r0) * Hh + ks * 2048 + swz;
    const unsigned short* aS1 = aS0 + (size_t)64 * Hh;
    const unsigned short* bS0 = w2b + (size_t)e * Dd * Hh + (size_t)(nt * 128 + r0) * Hh + ks * 2048 + swz;
    const unsigned short* bS1 = bS0 + (size_t)64 * Hh;

    float bsc = (ks == 0) ? 1.f : 0.f;
    float biasj[4];
#pragma unroll
    for (int j = 0; j < 4; j++)
      biasj[j] = b2e[nt * 128 + wn * 64 + j * 16 + fr] * bsc;

    f32x4 acc[4][4] = {};
    PIPELINE(2048 / 32);   // 64 K-steps per split

    float* yk = yb + (size_t)ks * Tt * Kk * Dd;
#pragma unroll
    for (int i = 0; i < 4; i++) {
      int rb = wm * 64 + i * 16 + kq * 4;
#pragma unroll
      for (int j = 0; j < 4; j++) {
        int col = nt * 128 + wn * 64 + j * 16 + fr;
#pragma unroll
        for (int rr = 0; rr < 4; rr++) {
          int grow = mt * 128 + rb + rr;
          if (grow < ce) {
            int en = le[grow];
            yk[(size_t)en * Dd + col] = acc[i][j][rr] + biasj[j];
          }
        }
      }
    }
  }
}

// ---------------- combine: out[t] = g0*(y0[2t]+y1[2t]) + g1*(y0[2t+1]+y1[2t+1]) --------
__global__ __launch_bounds__(256) void combine_kernel(
    const float* __restrict__ yb, const float* __restrict__ g2, float* __restrict__ out) {
  const int C4 = Dd / 4;
  const size_t HALF = (size_t)Tt * Kk * Dd / 4;   // in float4 units
  int i = blockIdx.x * blockDim.x + threadIdx.x;
  int t = i / C4;
  int c = i % C4;
  float g0 = g2[t * 2 + 0];
  float g1 = g2[t * 2 + 1];
  const float4* y4 = reinterpret_cast<const float4*>(yb);
  float4 a0 = y4[(size_t)(t * 2 + 0) * C4 + c];
  float4 a1 = y4[HALF + (size_t)(t * 2 + 0) * C4 + c];
  float4 b0 = y4[(size_t)(t * 2 + 1) * C4 + c];
  float4 b1v = y4[HALF + (size_t)(t * 2 + 1) * C4 + c];
  float4 o;
  o.x = g0 * (a0.x + a1.x) + g1 * (b0.x + b1v.x);
  o.y = g0 * (a0.y + a1.y) + g1 * (b0.y + b1v.y);
  o.z = g0 * (a0.z + a1.z) + g1 * (b0.z + b1v.z);
  o.w = g0 * (a0.w + a1.w) + g1 * (b0.w + b1v.w);
  reinterpret_cast<float4*>(out)[i] = o;
}

extern "C" void kernel_launch(void* const* d_in, const int* in_sizes, int n_in,
                              void* d_out, int out_size, void* d_ws, size_t ws_size,
                              hipStream_t stream) {
  const float* x  = (const float*)d_in[0];
  const float* Wr = (const float*)d_in[1];
  const float* br = (const float*)d_in[2];
  const float* W1 = (const float*)d_in[3];
  const float* b1 = (const float*)d_in[4];
  const float* W2 = (const float*)d_in[5];
  const float* b2 = (const float*)d_in[6];
  float* out = (float*)d_out;

  char* base = (char*)d_ws;
  size_t o = 0;
  auto alloc = [&](size_t n) { char* r = base + o; o += (n + 255) & ~(size_t)255; return r; };
  unsigned short* w1b = (unsigned short*)alloc((size_t)Ee * Hh * Dd * 2);
  unsigned short* w2b = (unsigned short*)alloc((size_t)Ee * Dd * Hh * 2);
  unsigned short* xg  = (unsigned short*)alloc((size_t)Ee * Tt * Dd * 2);
  unsigned short* hb  = (unsigned short*)alloc((size_t)(Tt * Kk + 256) * Hh * 2);  // +256 pad rows
  int* list  = (int*)alloc((size_t)Ee * Tt * 4);
  float* g2  = (float*)alloc((size_t)Tt * Kk * 4);
  int* cnt   = (int*)alloc(Ee * 4);
  int* meta  = (int*)alloc(32 * 4);
  if (o > ws_size) return;  // workspace too small: fail loudly (output stays poisoned)

  // xg (64MB) dead after gemm1; holds y[2][Tt*Kk][Dd] f32 (2 x 32MB).
  float* yb = (float*)xg;

  hipMemsetAsync(cnt, 0, Ee * 4, stream);

  cvt_kernel<<<4096, 256, 0, stream>>>(W1, w1b, Ee * Hh * Dd / 4);
  cvt_kernel<<<4096, 256, 0, stream>>>(W2, w2b, Ee * Dd * Hh / 4);

  router_kernel<<<Tt / 4, 256, 0, stream>>>(x, Wr, br, cnt, list, g2, xg);
  scan_kernel<<<1, 64, 0, stream>>>(cnt, meta);

  // 4 blocks/CU dispatched; grid-stride covers skew
  gemm1_kernel<<<1024, 256, 0, stream>>>(xg, w1b, b1, cnt, meta, hb);
  gemm2_kernel<<<1024, 256, 0, stream>>>(hb, w2b, b2, cnt, meta, list, yb);
  combine_kernel<<<(Tt * Dd / 4) / 256, 256, 0, stream>>>(yb, g2, out);
}

// Round 18
// 499.141 us; speedup vs baseline: 1.0848x; 1.0848x over previous
//
#include <hip/hip_runtime.h>
#include <hip/hip_bf16.h>

#define Dd 1024
#define Hh 4096
#define Ee 8
#define Tt 4096   // tokens = 2*2048
#define Kk 2

typedef __attribute__((ext_vector_type(8))) short short8;
typedef __attribute__((ext_vector_type(4))) float f32x4;

__device__ __forceinline__ unsigned short f2bf_bits(float f) {
  unsigned u = __builtin_bit_cast(unsigned, f);
  u += 0x7FFFu + ((u >> 16) & 1u);   // RNE (finite values)
  return (unsigned short)(u >> 16);
}

__device__ __forceinline__ void glds16(const void* g, void* l) {
  __builtin_amdgcn_global_load_lds(
      (const __attribute__((address_space(1))) unsigned int*)g,
      (__attribute__((address_space(3))) unsigned int*)l, 16, 0, 0);
}

// ---------------- fused fp32 -> bf16 conversion for W1 and W2 (one launch) ----------------
__global__ __launch_bounds__(256) void cvt_both_kernel(
    const float* __restrict__ w1, unsigned short* __restrict__ w1b,
    const float* __restrict__ w2, unsigned short* __restrict__ w2b, int n4each) {
  int i = blockIdx.x * blockDim.x + threadIdx.x;
  int stride = gridDim.x * blockDim.x;
  for (; i < 2 * n4each; i += stride) {
    const float4* src = (i < n4each) ? reinterpret_cast<const float4*>(w1)
                                     : reinterpret_cast<const float4*>(w2);
    ushort4* dst = (i < n4each) ? reinterpret_cast<ushort4*>(w1b)
                                : reinterpret_cast<ushort4*>(w2b);
    int k = (i < n4each) ? i : i - n4each;
    float4 v = src[k];
    ushort4 o;
    o.x = f2bf_bits(v.x);
    o.y = f2bf_bits(v.y);
    o.z = f2bf_bits(v.z);
    o.w = f2bf_bits(v.w);
    dst[k] = o;
  }
}

// ---------------- router: softmax + top-2 + expert lists + fused token gather ----------------
__global__ __launch_bounds__(256) void router_kernel(
    const float* __restrict__ x, const float* __restrict__ Wr, const float* __restrict__ br,
    int* __restrict__ cnt, int* __restrict__ list, float* __restrict__ g2,
    unsigned short* __restrict__ xg) {
  int t = blockIdx.x * 4 + (threadIdx.x >> 6);
  int lane = threadIdx.x & 63;
  const float* xr = x + (size_t)t * Dd;
  float pe[Ee];
#pragma unroll
  for (int e = 0; e < Ee; e++) pe[e] = 0.f;
  for (int d = lane; d < Dd; d += 64) {
    float xv = xr[d];
#pragma unroll
    for (int e = 0; e < Ee; e++) pe[e] += xv * Wr[e * Dd + d];
  }
#pragma unroll
  for (int e = 0; e < Ee; e++) {
    float v = pe[e];
#pragma unroll
    for (int s = 32; s > 0; s >>= 1) v += __shfl_xor(v, s);
    pe[e] = v + br[e];
  }
  int e0 = 0, e1 = 0, p0 = 0, p1 = 0;
  if (lane == 0) {
    float mx = pe[0];
#pragma unroll
    for (int e = 1; e < Ee; e++) mx = fmaxf(mx, pe[e]);
    float g[Ee];
    float sum = 0.f;
#pragma unroll
    for (int e = 0; e < Ee; e++) { g[e] = expf(pe[e] - mx); sum += g[e]; }
    float inv = 1.0f / sum;
    float g0v = g[0];
#pragma unroll
    for (int e = 1; e < Ee; e++) if (g[e] > g0v) { g0v = g[e]; e0 = e; }
    float g1v = -1.f;
#pragma unroll
    for (int e = 0; e < Ee; e++) if (e != e0 && g[e] > g1v) { g1v = g[e]; e1 = e; }
    g2[t * 2 + 0] = g0v * inv;
    g2[t * 2 + 1] = g1v * inv;
    p0 = atomicAdd(&cnt[e0], 1);
    list[e0 * Tt + p0] = t * 2;
    p1 = atomicAdd(&cnt[e1], 1);
    list[e1 * Tt + p1] = t * 2 + 1;
  }
  e0 = __shfl(e0, 0); p0 = __shfl(p0, 0);
  e1 = __shfl(e1, 0); p1 = __shfl(p1, 0);
  ushort4* r0 = (ushort4*)(xg + ((size_t)e0 * Tt + p0) * Dd);
  ushort4* r1 = (ushort4*)(xg + ((size_t)e1 * Tt + p1) * Dd);
  const float4* x4 = reinterpret_cast<const float4*>(xr);
  for (int c = lane; c < Dd / 4; c += 64) {
    float4 v = x4[c];
    ushort4 o;
    o.x = f2bf_bits(v.x);
    o.y = f2bf_bits(v.y);
    o.z = f2bf_bits(v.z);
    o.w = f2bf_bits(v.w);
    r0[c] = o;
    r1[c] = o;
  }
}

// meta: [0..7]=row offs, [8..15]=m_e=ceil(ce/128)
__global__ void scan_kernel(const int* __restrict__ cnt, int* __restrict__ meta) {
  if (threadIdx.x == 0 && blockIdx.x == 0) {
    int a = 0;
    for (int e = 0; e < Ee; e++) {
      meta[e] = a; a += cnt[e];
      meta[8 + e] = (cnt[e] + 127) >> 7;
    }
  }
}

// ================== 128x128 tile, BK=32, 4 waves (2x2) — r12/r14/r15-proven ==============
// 2-buffer counted pipeline (vmcnt(4), one tile in flight); LDS [row(128)][32] 64B rows,
// staging 4 lanes/row (fully-used lines); granule swizzle both sides -> 0 conflicts (HW).
#define STAGE(so_, k0)                                 \
  do {                                                 \
    glds16(aS0 + (k0), AsW + (so_) * 4096);            \
    glds16(aS1 + (k0), AsW + (so_) * 4096 + 2048);     \
    glds16(bS0 + (k0), BsW + (so_) * 4096);            \
    glds16(bS1 + (k0), BsW + (so_) * 4096 + 2048);     \
  } while (0)

#define COMPUTE(so_)                                                            \
  do {                                                                          \
    short8 af[4], bv[4];                                                        \
    _Pragma("unroll") for (int i = 0; i < 4; i++)                               \
        af[i] = *reinterpret_cast<const short8*>(                               \
            &As[(so_) * 4096 + (wm * 64 + i * 16 + fr) * 32 + gph]);            \
    _Pragma("unroll") for (int j = 0; j < 4; j++)                               \
        bv[j] = *reinterpret_cast<const short8*>(                               \
            &Bs[(so_) * 4096 + (wn * 64 + j * 16 + fr) * 32 + gph]);            \
    _Pragma("unroll") for (int i = 0; i < 4; i++)                               \
      _Pragma("unroll") for (int j = 0; j < 4; j++)                             \
          acc[i][j] = __builtin_amdgcn_mfma_f32_16x16x32_bf16(af[i], bv[j],     \
                                                              acc[i][j], 0, 0, 0); \
  } while (0)

#define PIPELINE(NKT)                                              \
  do {                                                             \
    STAGE(0, 0);                                                   \
    STAGE(1, 32);                                                  \
    for (int kt = 0; kt <= (NKT)-3; ++kt) {                        \
      int so = kt & 1;                                             \
      asm volatile("s_waitcnt vmcnt(4)" ::: "memory");             \
      __builtin_amdgcn_s_barrier();                                \
      COMPUTE(so);                                                 \
      __builtin_amdgcn_s_barrier();                                \
      STAGE(so, (kt + 2) * 32);                                    \
    }                                                              \
    asm volatile("s_waitcnt vmcnt(4)" ::: "memory");               \
    __builtin_amdgcn_s_barrier();                                  \
    COMPUTE(((NKT)-2) & 1);                                        \
    asm volatile("s_waitcnt vmcnt(0)" ::: "memory");               \
    __builtin_amdgcn_s_barrier();                                  \
    COMPUTE(((NKT)-1) & 1);                                        \
  } while (0)

// ---------------- GEMM1 (r15): h = gelu(xg @ W1[e]^T + b1[e]) -> bf16 ------------------
__global__ __launch_bounds__(256) void gemm1_kernel(
    const unsigned short* __restrict__ xg, const unsigned short* __restrict__ w1b,
    const float* __restrict__ b1,
    const int* __restrict__ cnt, const int* __restrict__ meta,
    unsigned short* __restrict__ hb) {
  int e = blockIdx.x & 7;
  int G = gridDim.x >> 3;
  int m_e = meta[8 + e];
  int ce = cnt[e], off_e = meta[e];
  int span = m_e * (Hh / 128);

  __shared__ short As[2 * 4096];
  __shared__ short Bs[2 * 4096];

  int tid = threadIdx.x;
  int lane = tid & 63;
  int w = tid >> 6;
  int wm = w >> 1, wn = w & 1;
  int fr = lane & 15, kq = lane >> 4;

  int r0 = tid >> 2;
  int swz = ((tid & 3) ^ ((r0 >> 1) & 3)) << 3;
  short* AsW = &As[w * 512];
  short* BsW = &Bs[w * 512];
  int gph = (kq ^ ((fr >> 1) & 3)) << 3;
  const float* b1e = b1 + (size_t)e * Hh;

  for (int local = blockIdx.x >> 3; local < span; local += G) {
    int nt = local / m_e, mt = local % m_e;
    __syncthreads();

    const unsigned short* aS0 = xg + (size_t)e * Tt * Dd + (size_t)(mt * 128 + r0) * Dd + swz;
    const unsigned short* aS1 = aS0 + (size_t)64 * Dd;
    const unsigned short* bS0 = w1b + (size_t)e * Hh * Dd + (size_t)(nt * 128 + r0) * Dd + swz;
    const unsigned short* bS1 = bS0 + (size_t)64 * Dd;

    float biasj[4];
#pragma unroll
    for (int j = 0; j < 4; j++) biasj[j] = b1e[nt * 128 + wn * 64 + j * 16 + fr];
    asm volatile("s_waitcnt vmcnt(0)" ::: "memory");

    f32x4 acc[4][4] = {};
    PIPELINE(Dd / 32);

#pragma unroll
    for (int i = 0; i < 4; i++) {
      int rb = wm * 64 + i * 16 + kq * 4;
#pragma unroll
      for (int j = 0; j < 4; j++) {
        int col = nt * 128 + wn * 64 + j * 16 + fr;
#pragma unroll
        for (int rr = 0; rr < 4; rr++) {
          int grow = mt * 128 + rb + rr;
          if (grow < ce) {
            float v = acc[i][j][rr] + biasj[j];
            v = 0.5f * v * (1.0f + erff(v * 0.70710678118654752f));
            hb[(size_t)(off_e + grow) * Hh + col] = f2bf_bits(v);
          }
        }
      }
    }
  }
}

// ---------------- GEMM2 (r14, best measured 174us): y[en] = h @ W2[e]^T + b2[e] --------
__global__ __launch_bounds__(256) void gemm2_kernel(
    const unsigned short* __restrict__ hb, const unsigned short* __restrict__ w2b,
    const float* __restrict__ b2,
    const int* __restrict__ cnt, const int* __restrict__ meta, const int* __restrict__ list,
    float* __restrict__ y) {
  int e = blockIdx.x & 7;
  int G = gridDim.x >> 3;
  int m_e = meta[8 + e];
  int ce = cnt[e], off_e = meta[e];
  int span = m_e * (Dd / 128);

  __shared__ short As[2 * 4096];
  __shared__ short Bs[2 * 4096];

  int tid = threadIdx.x;
  int lane = tid & 63;
  int w = tid >> 6;
  int wm = w >> 1, wn = w & 1;
  int fr = lane & 15, kq = lane >> 4;

  int r0 = tid >> 2;
  int swz = ((tid & 3) ^ ((r0 >> 1) & 3)) << 3;
  short* AsW = &As[w * 512];
  short* BsW = &Bs[w * 512];
  int gph = (kq ^ ((fr >> 1) & 3)) << 3;
  const int* le = list + e * Tt;
  const float* b2e = b2 + (size_t)e * Dd;

  for (int local = blockIdx.x >> 3; local < span; local += G) {
    int nt = local / m_e, mt = local % m_e;
    __syncthreads();

    int ra0 = mt * 128 + r0;      if (ra0 >= ce) ra0 = ce - 1;
    int ra1 = mt * 128 + r0 + 64; if (ra1 >= ce) ra1 = ce - 1;
    const unsigned short* aS0 = hb + (size_t)(off_e + ra0) * Hh + swz;
    const unsigned short* aS1 = hb + (size_t)(off_e + ra1) * Hh + swz;
    const unsigned short* bS0 = w2b + (size_t)e * Dd * Hh + (size_t)(nt * 128 + r0) * Hh + swz;
    const unsigned short* bS1 = bS0 + (size_t)64 * Hh;

    float biasj[4];
#pragma unroll
    for (int j = 0; j < 4; j++) biasj[j] = b2e[nt * 128 + wn * 64 + j * 16 + fr];
    asm volatile("s_waitcnt vmcnt(0)" ::: "memory");

    f32x4 acc[4][4] = {};
    PIPELINE(Hh / 32);   // full K = 4096, 128 steps

#pragma unroll
    for (int i = 0; i < 4; i++) {
      int rb = wm * 64 + i * 16 + kq * 4;
#pragma unroll
      for (int j = 0; j < 4; j++) {
        int col = nt * 128 + wn * 64 + j * 16 + fr;
#pragma unroll
        for (int rr = 0; rr < 4; rr++) {
          int grow = mt * 128 + rb + rr;
          if (grow < ce) {
            int en = le[grow];
            y[(size_t)en * Dd + col] = acc[i][j][rr] + biasj[j];
          }
        }
      }
    }
  }
}

// ---------------- combine: out[t] = g0*y[2t] + g1*y[2t+1] ----------------
__global__ __launch_bounds__(256) void combine_kernel(
    const float* __restrict__ y, const float* __restrict__ g2, float* __restrict__ out) {
  const int C4 = Dd / 4;
  int i = blockIdx.x * blockDim.x + threadIdx.x;
  int t = i / C4;
  int c = i % C4;
  float g0 = g2[t * 2 + 0];
  float g1 = g2[t * 2 + 1];
  float4 y0 = reinterpret_cast<const float4*>(y)[(size_t)(t * 2 + 0) * C4 + c];
  float4 y1 = reinterpret_cast<const float4*>(y)[(size_t)(t * 2 + 1) * C4 + c];
  float4 o;
  o.x = g0 * y0.x + g1 * y1.x;
  o.y = g0 * y0.y + g1 * y1.y;
  o.z = g0 * y0.z + g1 * y1.z;
  o.w = g0 * y0.w + g1 * y1.w;
  reinterpret_cast<float4*>(out)[i] = o;
}

extern "C" void kernel_launch(void* const* d_in, const int* in_sizes, int n_in,
                              void* d_out, int out_size, void* d_ws, size_t ws_size,
                              hipStream_t stream) {
  const float* x  = (const float*)d_in[0];
  const float* Wr = (const float*)d_in[1];
  const float* br = (const float*)d_in[2];
  const float* W1 = (const float*)d_in[3];
  const float* b1 = (const float*)d_in[4];
  const float* W2 = (const float*)d_in[5];
  const float* b2 = (const float*)d_in[6];
  float* out = (float*)d_out;

  char* base = (char*)d_ws;
  size_t o = 0;
  auto alloc = [&](size_t n) { char* r = base + o; o += (n + 255) & ~(size_t)255; return r; };
  unsigned short* w1b = (unsigned short*)alloc((size_t)Ee * Hh * Dd * 2);
  unsigned short* w2b = (unsigned short*)alloc((size_t)Ee * Dd * Hh * 2);
  unsigned short* xg  = (unsigned short*)alloc((size_t)Ee * Tt * Dd * 2);
  unsigned short* hb  = (unsigned short*)alloc((size_t)(Tt * Kk + 256) * Hh * 2);
  int* list  = (int*)alloc((size_t)Ee * Tt * 4);
  float* g2  = (float*)alloc((size_t)Tt * Kk * 4);
  int* cnt   = (int*)alloc(Ee * 4);
  int* meta  = (int*)alloc(32 * 4);
  if (o > ws_size) return;  // workspace too small: fail loudly (output stays poisoned)

  // w1b (64MB) dead after gemm1; holds y[Tt*Kk][Dd] f32 (32MB).
  float* y = (float*)w1b;

  hipMemsetAsync(cnt, 0, Ee * 4, stream);

  cvt_both_kernel<<<8192, 256, 0, stream>>>(W1, w1b, W2, w2b, Ee * Hh * Dd / 4);
  router_kernel<<<Tt / 4, 256, 0, stream>>>(x, Wr, br, cnt, list, g2, xg);
  scan_kernel<<<1, 64, 0, stream>>>(cnt, meta);

  gemm1_kernel<<<2048, 256, 0, stream>>>(xg, w1b, b1, cnt, meta, hb);
  gemm2_kernel<<<1024, 256, 0, stream>>>(hb, w2b, b2, cnt, meta, list, y);
  combine_kernel<<<(Tt * Dd / 4) / 256, 256, 0, stream>>>(y, g2, out);
}